// Round 1
// baseline (267.872 us; speedup 1.0000x reference)
//
#include <hip/hip_runtime.h>
#include <stdint.h>

#define SA 1027
#define MROWS 8216
#define MPAD 8320
#define SPAD 1088
#define ATTM 8192

typedef __attribute__((ext_vector_type(8))) short short8;
typedef __attribute__((ext_vector_type(4))) float f32x4;

typedef const __attribute__((address_space(1))) uint8_t* gas1;
typedef __attribute__((address_space(3))) uint8_t* las3;

__device__ __forceinline__ void gload16(const void* g, void* l){
  __builtin_amdgcn_global_load_lds((gas1)g, (las3)l, 16, 0, 0);
}

__device__ __forceinline__ uint16_t f2bf(float f){
  uint32_t x = __builtin_bit_cast(uint32_t, f);
  x = (x + 0x7fffu + ((x >> 16) & 1u)) >> 16;
  return (uint16_t)x;
}
__device__ __forceinline__ float bf2f(uint16_t u){
  uint32_t x = ((uint32_t)u) << 16;
  return __builtin_bit_cast(float, x);
}

__device__ __forceinline__ f32x4 mfma16(short8 a, short8 b, f32x4 c){
  return __builtin_amdgcn_mfma_f32_16x16x32_bf16(a, b, c, 0, 0, 0);
}

// ---------------- prep: weights/biases -> bf16 ws ----------------
__global__ __launch_bounds__(256) void prep_wb(
    const float* __restrict__ Wq, const float* __restrict__ Wk,
    const float* __restrict__ Wv, const float* __restrict__ Wo,
    const float* __restrict__ bq, const float* __restrict__ bk,
    const float* __restrict__ bv, const float* __restrict__ bo,
    uint16_t* __restrict__ W, float* __restrict__ bias){
  const int gid = blockIdx.x*256 + threadIdx.x;
  if (gid < 1048576){
    const int w = gid >> 18;
    const int off = (gid & 262143) << 2;
    const float* src = (w==0) ? Wq : (w==1) ? Wk : (w==2) ? Wv : Wo;
    const float4 v = *(const float4*)(src + off);
    ushort4 u;
    u.x = f2bf(v.x); u.y = f2bf(v.y); u.z = f2bf(v.z); u.w = f2bf(v.w);
    *(ushort4*)(W + ((size_t)w << 20) + off) = u;
  } else if (gid < 1048576 + 1024){
    const int i = (gid - 1048576) << 2;
    const int w = i >> 10;
    const int off = i & 1023;
    const float* src = (w==0) ? bq : (w==1) ? bk : (w==2) ? bv : bo;
    *(float4*)(bias + i) = *(const float4*)(src + off);
  }
}

// ---------------- prep: X = [aug_cnn; aug_llm] bf16, padded to MPAD rows ----
__global__ __launch_bounds__(256) void prep_X(
    const float* __restrict__ cnn, const float* __restrict__ llm,
    const float* __restrict__ ee, const float* __restrict__ em,
    const float* __restrict__ ep, uint16_t* __restrict__ X){
  const int row = blockIdx.x;
  const int c4 = threadIdx.x << 2;
  float4 v = {0.f,0.f,0.f,0.f};
  if (row < MROWS){
    const int cb = row / SA;
    const int s = row - cb*SA;
    const int c = cb >> 2, b = cb & 3;
    const float* src;
    if (s < 1024) src = (c ? llm : cnn) + ((size_t)(b*1024 + s))*1024 + c4;
    else src = ((s == 1024) ? ee : (s == 1025) ? em : ep) + c4;
    v = *(const float4*)src;
  }
  ushort4 u;
  u.x = f2bf(v.x); u.y = f2bf(v.y); u.z = f2bf(v.z); u.w = f2bf(v.w);
  *(ushort4*)(X + (size_t)row*1024 + c4) = u;
}

// ---------------- 128x128 bf16 GEMM, C[m][n] = sum_k A[m][k]*B[n][k] + bias[n]
__global__ __launch_bounds__(256) void gemm_bt(
    const uint16_t* __restrict__ A, const uint16_t* __restrict__ B,
    const float* __restrict__ bias, uint16_t* __restrict__ C,
    int K, int lda, int ldb, int ldc){
  __shared__ __align__(16) uint8_t smA[16384];
  __shared__ __align__(16) uint8_t smB[16384];
  const int tid = threadIdx.x;
  const int lane = tid & 63, wid = tid >> 6;
  const int l15 = lane & 15, l4 = lane >> 4;
  const int bn = blockIdx.x, bm = blockIdx.y;
  const int wr = wid >> 1, wc = wid & 1;

  f32x4 acc[4][4];
  #pragma unroll
  for (int i = 0; i < 4; ++i)
    #pragma unroll
    for (int j = 0; j < 4; ++j) acc[i][j] = (f32x4){0.f,0.f,0.f,0.f};

  const int srow = lane >> 3;
  const int schunk = lane & 7;
  const int KT = K >> 6;
  for (int kt = 0; kt < KT; ++kt){
    __syncthreads();
    #pragma unroll
    for (int j = 0; j < 4; ++j){
      const int cj = wid*4 + j;
      const int row = cj*8 + srow;
      const int gch = schunk ^ (row & 7);   // pre-swizzled global source (rule 21)
      gload16(A + (size_t)(bm*128 + row)*lda + kt*64 + gch*8, smA + cj*1024);
      gload16(B + (size_t)(bn*128 + row)*ldb + kt*64 + gch*8, smB + cj*1024);
    }
    __syncthreads();
    #pragma unroll
    for (int kk = 0; kk < 2; ++kk){
      short8 af[4], bfr[4];
      #pragma unroll
      for (int i = 0; i < 4; ++i){
        const int row = wr*64 + i*16 + l15;
        af[i] = *(const short8*)(smA + ((row*128 + kk*64 + l4*16) ^ ((row & 7) << 4)));
      }
      #pragma unroll
      for (int j = 0; j < 4; ++j){
        const int row = wc*64 + j*16 + l15;
        bfr[j] = *(const short8*)(smB + ((row*128 + kk*64 + l4*16) ^ ((row & 7) << 4)));
      }
      #pragma unroll
      for (int i = 0; i < 4; ++i)
        #pragma unroll
        for (int j = 0; j < 4; ++j)
          acc[i][j] = mfma16(af[i], bfr[j], acc[i][j]);
    }
  }
  #pragma unroll
  for (int j = 0; j < 4; ++j){
    const int n = bn*128 + wc*64 + j*16 + l15;
    const float bb = bias[n];
    #pragma unroll
    for (int i = 0; i < 4; ++i){
      const int m0 = bm*128 + wr*64 + i*16 + l4*4;
      #pragma unroll
      for (int r = 0; r < 4; ++r)
        C[(size_t)(m0 + r)*ldc + n] = f2bf(acc[i][j][r] + bb);
    }
  }
}

// ---------------- V transpose: Vt[(cb*16+h)*64 + d][s], zero-padded to SPAD --
__global__ __launch_bounds__(256) void vtrans(
    const uint16_t* __restrict__ Y, uint16_t* __restrict__ Vt){
  __shared__ uint16_t t[64][65];
  const int bid = blockIdx.x;
  const int st = bid % 17, cbh = bid / 17;
  const int s0 = st*64;
  const int tid = threadIdx.x;
  const int a = tid >> 2, g = tid & 3;
  const int cb = cbh >> 4, h = cbh & 15;
  const int s = s0 + a;
  short8 v0 = {0,0,0,0,0,0,0,0}, v1 = {0,0,0,0,0,0,0,0};
  if (s < SA){
    const uint16_t* p = Y + ((size_t)cb*SA + s)*3072 + 2048 + h*64 + g*16;
    v0 = *(const short8*)p;
    v1 = *(const short8*)(p + 8);
  }
  #pragma unroll
  for (int i=0;i<8;i++){ t[a][g*16+i] = (uint16_t)v0[i]; t[a][g*16+8+i] = (uint16_t)v1[i]; }
  __syncthreads();
  short8 w0, w1;
  #pragma unroll
  for (int i=0;i<8;i++){ w0[i] = (short)t[g*16+i][a]; w1[i] = (short)t[g*16+8+i][a]; }
  uint16_t* o = Vt + ((size_t)cbh*64 + a)*SPAD + s0 + g*16;
  *(short8*)o = w0;
  *(short8*)(o + 8) = w1;
}

// ---------------- flash attention ----------------
// grid: 2048 = (2*4*16 insts) * 16 q-blocks ; 4 waves, each 16 q-rows
__global__ __launch_bounds__(256) void attn_k(
    const uint16_t* __restrict__ Y, const uint16_t* __restrict__ Vt,
    uint16_t* __restrict__ att){
  __shared__ __align__(16) uint8_t smK[8192];
  __shared__ __align__(16) uint8_t smV[8192];
  __shared__ __align__(16) uint8_t smP[8192];
  const int tid = threadIdx.x;
  const int lane = tid & 63, wid = tid >> 6;
  const int l15 = lane & 15, l4 = lane >> 4;
  const int bid = blockIdx.x;
  const int inst = bid >> 4, qb = bid & 15;
  const int h = inst & 15, cb = inst >> 4;
  const size_t yrow0 = (size_t)cb * SA;
  const int q0 = qb*64 + wid*16;
  const size_t vbase = (size_t)inst * 64 * SPAD;

  short8 qf[2];
  {
    const uint16_t* p = Y + (yrow0 + q0 + l15)*3072 + h*64 + l4*8;
    qf[0] = *(const short8*)p;
    qf[1] = *(const short8*)(p + 32);
  }
  f32x4 o[4];
  float mrow[4], lrow[4];
  #pragma unroll
  for (int i=0;i<4;i++){ o[i] = (f32x4){0.f,0.f,0.f,0.f}; mrow[i] = -3e38f; lrow[i] = 0.f; }

  const int srow = lane >> 3, schunk = lane & 7;
  uint8_t* const pb = smP + wid*2048;

  for (int kt = 0; kt < 17; ++kt){
    const int s0 = kt*64;
    __syncthreads();
    #pragma unroll
    for (int j = 0; j < 2; ++j){
      const int cj = wid*2 + j;
      const int row = cj*8 + srow;
      const int gch = schunk ^ (row & 7);
      gload16(Y + (yrow0 + s0 + row)*3072 + 1024 + h*64 + gch*8, smK + cj*1024);
      gload16(Vt + vbase + (size_t)row*SPAD + s0 + gch*8, smV + cj*1024);
    }
    __syncthreads();

    f32x4 sf[4];
    #pragma unroll
    for (int nt = 0; nt < 4; ++nt){
      f32x4 a = (f32x4){0.f,0.f,0.f,0.f};
      #pragma unroll
      for (int kk = 0; kk < 2; ++kk){
        const int row = nt*16 + l15;
        short8 kf = *(const short8*)(smK + ((row*128 + kk*64 + l4*16) ^ ((row & 7) << 4)));
        a = mfma16(qf[kk], kf, a);
      }
      sf[nt] = a * 0.125f;
      if (s0 + nt*16 + l15 >= SA) sf[nt] = (f32x4){-3e38f,-3e38f,-3e38f,-3e38f};
    }

    float tm[4];
    #pragma unroll
    for (int r=0;r<4;r++) tm[r] = fmaxf(fmaxf(sf[0][r], sf[1][r]), fmaxf(sf[2][r], sf[3][r]));
    #pragma unroll
    for (int m=1; m<16; m<<=1)
      #pragma unroll
      for (int r=0;r<4;r++) tm[r] = fmaxf(tm[r], __shfl_xor(tm[r], m));

    float mnew[4], scl[4], rsum[4];
    #pragma unroll
    for (int r=0;r<4;r++){
      mnew[r] = fmaxf(mrow[r], tm[r]);
      scl[r] = __expf(mrow[r] - mnew[r]);
      rsum[r] = 0.f;
    }
    #pragma unroll
    for (int nt=0;nt<4;nt++)
      #pragma unroll
      for (int r=0;r<4;r++){
        const float p = __expf(sf[nt][r] - mnew[r]);
        sf[nt][r] = p;
        rsum[r] += p;
      }
    #pragma unroll
    for (int m=1; m<16; m<<=1)
      #pragma unroll
      for (int r=0;r<4;r++) rsum[r] += __shfl_xor(rsum[r], m);
    #pragma unroll
    for (int r=0;r<4;r++){
      lrow[r] = lrow[r]*scl[r] + rsum[r];
      mrow[r] = mnew[r];
    }
    #pragma unroll
    for (int dt=0;dt<4;dt++)
      #pragma unroll
      for (int r=0;r<4;r++) o[dt][r] *= scl[r];

    // P -> LDS (bf16) in C/D layout, read back in A-frag layout (swizzled)
    #pragma unroll
    for (int nt=0;nt<4;nt++)
      #pragma unroll
      for (int r=0;r<4;r++){
        const int rq = l4*4 + r;
        *(uint16_t*)(pb + ((rq*128 + (nt*16 + l15)*2) ^ ((rq & 7) << 4))) = f2bf(sf[nt][r]);
      }

    #pragma unroll
    for (int kk=0;kk<2;kk++){
      short8 pf = *(const short8*)(pb + ((l15*128 + kk*64 + l4*16) ^ ((l15 & 7) << 4)));
      #pragma unroll
      for (int dt=0;dt<4;dt++){
        const int vr = dt*16 + l15;
        short8 vf = *(const short8*)(smV + ((vr*128 + kk*64 + l4*16) ^ ((vr & 7) << 4)));
        o[dt] = mfma16(pf, vf, o[dt]);
      }
    }
  }

  const size_t arow0 = (size_t)cb*1024 + q0;
  #pragma unroll
  for (int dt=0;dt<4;dt++)
    #pragma unroll
    for (int r=0;r<4;r++){
      const float v = o[dt][r] / lrow[r];
      att[(arow0 + l4*4 + r)*1024 + h*64 + dt*16 + l15] = f2bf(v);
    }
}

// ---------------- fused residual + LayerNorm -> f32 out ----------------
__global__ __launch_bounds__(256) void ln_out(
    const uint16_t* __restrict__ Op, const float* __restrict__ cnn,
    const float* __restrict__ llm, const float* __restrict__ g,
    const float* __restrict__ b, float* __restrict__ out){
  const int row = blockIdx.x;
  const int c = row >> 12, bq = row & 4095;
  const int tid = threadIdx.x;
  const ushort4 u = *(const ushort4*)(Op + (size_t)row*1024 + (tid<<2));
  const float4 rv = *(const float4*)((c ? llm : cnn) + (size_t)bq*1024 + (tid<<2));
  const float x0 = bf2f(u.x) + rv.x;
  const float x1 = bf2f(u.y) + rv.y;
  const float x2 = bf2f(u.z) + rv.z;
  const float x3 = bf2f(u.w) + rv.w;
  float s1 = x0+x1+x2+x3;
  float s2 = x0*x0+x1*x1+x2*x2+x3*x3;
  #pragma unroll
  for (int m=1;m<64;m<<=1){ s1 += __shfl_xor(s1,m); s2 += __shfl_xor(s2,m); }
  __shared__ float r1[4], r2[4];
  const int wid = tid >> 6, lane = tid & 63;
  if (lane == 0){ r1[wid] = s1; r2[wid] = s2; }
  __syncthreads();
  s1 = r1[0]+r1[1]+r1[2]+r1[3];
  s2 = r2[0]+r2[1]+r2[2]+r2[3];
  const float mu = s1 * 0.0009765625f;
  const float var = s2 * 0.0009765625f - mu*mu;
  const float rs = rsqrtf(var + 1e-5f);
  const float4 gv = *(const float4*)(g + (tid<<2));
  const float4 bv = *(const float4*)(b + (tid<<2));
  float4 ov;
  ov.x = (x0 - mu)*rs*gv.x + bv.x;
  ov.y = (x1 - mu)*rs*gv.y + bv.y;
  ov.z = (x2 - mu)*rs*gv.z + bv.z;
  ov.w = (x3 - mu)*rs*gv.w + bv.w;
  *(float4*)(out + ((size_t)c << 22) + (size_t)bq*1024 + (tid<<2)) = ov;
}

extern "C" void kernel_launch(void* const* d_in, const int* in_sizes, int n_in,
                              void* d_out, int out_size, void* d_ws, size_t ws_size,
                              hipStream_t stream){
  const float* cnn = (const float*)d_in[0];
  const float* llm = (const float*)d_in[1];
  const float* Wq  = (const float*)d_in[2];
  const float* bq  = (const float*)d_in[3];
  const float* Wk  = (const float*)d_in[4];
  const float* bk  = (const float*)d_in[5];
  const float* Wv  = (const float*)d_in[6];
  const float* bv  = (const float*)d_in[7];
  const float* Wo  = (const float*)d_in[8];
  const float* bo  = (const float*)d_in[9];
  const float* lng = (const float*)d_in[10];
  const float* lnb = (const float*)d_in[11];
  const float* ee  = (const float*)d_in[12];
  const float* em  = (const float*)d_in[13];
  const float* ep  = (const float*)d_in[14];

  uint8_t* ws = (uint8_t*)d_ws;
  uint16_t* X    = (uint16_t*)(ws + 0);           // 8320*1024*2  = 17,039,360
  uint16_t* W    = (uint16_t*)(ws + 17039360);    // 4096*1024*2  =  8,388,608
  float*    bias = (float*)   (ws + 25427968);    // 4096*4       =     16,384
  uint16_t* Y    = (uint16_t*)(ws + 25444352);    // 8320*3072*2  = 51,118,080
  uint16_t* Vt   = (uint16_t*)(ws + 76562432);    // 8192*1088*2  = 17,825,792
  uint16_t* att  = (uint16_t*)(ws + 94388224);    // 8192*1024*2  = 16,777,216
  uint16_t* Op   = X;                              // reuse X region after QKV GEMM
  float* out = (float*)d_out;

  prep_wb<<<4100, 256, 0, stream>>>(Wq, Wk, Wv, Wo, bq, bk, bv, bo, W, bias);
  prep_X<<<MPAD, 256, 0, stream>>>(cnn, llm, ee, em, ep, X);
  gemm_bt<<<dim3(24, 65), 256, 0, stream>>>(X, W, bias, Y, 1024, 1024, 1024, 3072);
  vtrans<<<128*17, 256, 0, stream>>>(Y, Vt);
  attn_k<<<2048, 256, 0, stream>>>(Y, Vt, att);
  gemm_bt<<<dim3(8, 64), 256, 0, stream>>>(att, W + 3145728, bias + 3072, Op, 1024, 1024, 1024, 1024);
  ln_out<<<ATTM, 256, 0, stream>>>(Op, cnn, llm, lng, lnb, out);
}

// Round 2
// 191.159 us; speedup vs baseline: 1.4013x; 1.4013x over previous
//
#include <hip/hip_runtime.h>
#include <stdint.h>

#define SA 1027
#define MROWS 8216
#define MPAD 8320
#define SPAD 1088
#define ATTM 8192

typedef __attribute__((ext_vector_type(8))) short short8;
typedef __attribute__((ext_vector_type(4))) float f32x4;
typedef __attribute__((ext_vector_type(2))) unsigned int u32x2;

typedef const __attribute__((address_space(1))) uint8_t* gas1;
typedef __attribute__((address_space(3))) uint8_t* las3;

__device__ __forceinline__ void gload16(const void* g, void* l){
  __builtin_amdgcn_global_load_lds((gas1)g, (las3)l, 16, 0, 0);
}

__device__ __forceinline__ uint16_t f2bf(float f){
  uint32_t x = __builtin_bit_cast(uint32_t, f);
  x = (x + 0x7fffu + ((x >> 16) & 1u)) >> 16;
  return (uint16_t)x;
}
__device__ __forceinline__ float bf2f(uint16_t u){
  uint32_t x = ((uint32_t)u) << 16;
  return __builtin_bit_cast(float, x);
}

__device__ __forceinline__ f32x4 mfma16(short8 a, short8 b, f32x4 c){
  return __builtin_amdgcn_mfma_f32_16x16x32_bf16(a, b, c, 0, 0, 0);
}

// log2(e)/8 — folded into Q at the QKV GEMM epilogue
#define QSCALE 0.18033688011112042f

// ---------------- prep: weights/biases -> bf16 ws ----------------
__global__ __launch_bounds__(256) void prep_wb(
    const float* __restrict__ Wq, const float* __restrict__ Wk,
    const float* __restrict__ Wv, const float* __restrict__ Wo,
    const float* __restrict__ bq, const float* __restrict__ bk,
    const float* __restrict__ bv, const float* __restrict__ bo,
    uint16_t* __restrict__ W, float* __restrict__ bias){
  const int gid = blockIdx.x*256 + threadIdx.x;
  if (gid < 1048576){
    const int w = gid >> 18;
    const int off = (gid & 262143) << 2;
    const float* src = (w==0) ? Wq : (w==1) ? Wk : (w==2) ? Wv : Wo;
    const float4 v = *(const float4*)(src + off);
    ushort4 u;
    u.x = f2bf(v.x); u.y = f2bf(v.y); u.z = f2bf(v.z); u.w = f2bf(v.w);
    *(ushort4*)(W + ((size_t)w << 20) + off) = u;
  } else if (gid < 1048576 + 1024){
    const int i = (gid - 1048576) << 2;
    const int w = i >> 10;
    const int off = i & 1023;
    const float* src = (w==0) ? bq : (w==1) ? bk : (w==2) ? bv : bo;
    *(float4*)(bias + i) = *(const float4*)(src + off);
  }
}

// ---------------- prep: X = [aug_cnn; aug_llm] bf16, padded to MPAD rows ----
__global__ __launch_bounds__(256) void prep_X(
    const float* __restrict__ cnn, const float* __restrict__ llm,
    const float* __restrict__ ee, const float* __restrict__ em,
    const float* __restrict__ ep, uint16_t* __restrict__ X){
  const int row = blockIdx.x;
  const int c4 = threadIdx.x << 2;
  float4 v = {0.f,0.f,0.f,0.f};
  if (row < MROWS){
    const int cb = row / SA;
    const int s = row - cb*SA;
    const int c = cb >> 2, b = cb & 3;
    const float* src;
    if (s < 1024) src = (c ? llm : cnn) + ((size_t)(b*1024 + s))*1024 + c4;
    else src = ((s == 1024) ? ee : (s == 1025) ? em : ep) + c4;
    v = *(const float4*)src;
  }
  ushort4 u;
  u.x = f2bf(v.x); u.y = f2bf(v.y); u.z = f2bf(v.z); u.w = f2bf(v.w);
  *(ushort4*)(X + (size_t)row*1024 + c4) = u;
}

// ---------------- 128x128 bf16 GEMM, C[m][n] = (sum_k A[m][k]*B[n][k]+bias[n])*sc
__global__ __launch_bounds__(256) void gemm_bt(
    const uint16_t* __restrict__ A, const uint16_t* __restrict__ B,
    const float* __restrict__ bias, uint16_t* __restrict__ C,
    int K, int lda, int ldb, int ldc, float qscale, int qcols){
  __shared__ __align__(16) uint8_t smA[16384];
  __shared__ __align__(16) uint8_t smB[16384];
  const int tid = threadIdx.x;
  const int lane = tid & 63, wid = tid >> 6;
  const int l15 = lane & 15, l4 = lane >> 4;
  // XCD-aware block swizzle (grid sizes are multiples of 8)
  const int orig = blockIdx.y * gridDim.x + blockIdx.x;
  const int cpx = (gridDim.x * gridDim.y) >> 3;
  const int swz = (orig & 7) * cpx + (orig >> 3);
  const int bn = swz % gridDim.x;
  const int bm = swz / gridDim.x;
  const int wr = wid >> 1, wc = wid & 1;

  f32x4 acc[4][4];
  #pragma unroll
  for (int i = 0; i < 4; ++i)
    #pragma unroll
    for (int j = 0; j < 4; ++j) acc[i][j] = (f32x4){0.f,0.f,0.f,0.f};

  const int srow = lane >> 3;
  const int schunk = lane & 7;
  const int KT = K >> 6;
  for (int kt = 0; kt < KT; ++kt){
    __syncthreads();
    #pragma unroll
    for (int j = 0; j < 4; ++j){
      const int cj = wid*4 + j;
      const int row = cj*8 + srow;
      const int gch = schunk ^ (row & 7);   // pre-swizzled global source
      gload16(A + (size_t)(bm*128 + row)*lda + kt*64 + gch*8, smA + cj*1024);
      gload16(B + (size_t)(bn*128 + row)*ldb + kt*64 + gch*8, smB + cj*1024);
    }
    __syncthreads();
    #pragma unroll
    for (int kk = 0; kk < 2; ++kk){
      short8 af[4], bfr[4];
      #pragma unroll
      for (int i = 0; i < 4; ++i){
        const int row = wr*64 + i*16 + l15;
        af[i] = *(const short8*)(smA + ((row*128 + kk*64 + l4*16) ^ ((row & 7) << 4)));
      }
      #pragma unroll
      for (int j = 0; j < 4; ++j){
        const int row = wc*64 + j*16 + l15;
        bfr[j] = *(const short8*)(smB + ((row*128 + kk*64 + l4*16) ^ ((row & 7) << 4)));
      }
      #pragma unroll
      for (int i = 0; i < 4; ++i)
        #pragma unroll
        for (int j = 0; j < 4; ++j)
          acc[i][j] = mfma16(af[i], bfr[j], acc[i][j]);
    }
  }
  #pragma unroll
  for (int j = 0; j < 4; ++j){
    const int n = bn*128 + wc*64 + j*16 + l15;
    const float bb = bias[n];
    const float sc = (n < qcols) ? qscale : 1.0f;
    #pragma unroll
    for (int i = 0; i < 4; ++i){
      const int m0 = bm*128 + wr*64 + i*16 + l4*4;
      #pragma unroll
      for (int r = 0; r < 4; ++r)
        C[(size_t)(m0 + r)*ldc + n] = f2bf((acc[i][j][r] + bb) * sc);
    }
  }
}

// ---------------- V transpose: Vt[(cb*16+h)*64 + d][s], zero-padded to SPAD --
__global__ __launch_bounds__(256) void vtrans(
    const uint16_t* __restrict__ Y, uint16_t* __restrict__ Vt){
  __shared__ uint16_t t[64][65];
  const int bid = blockIdx.x;
  const int st = bid % 17, cbh = bid / 17;
  const int s0 = st*64;
  const int tid = threadIdx.x;
  const int a = tid >> 2, g = tid & 3;
  const int cb = cbh >> 4, h = cbh & 15;
  const int s = s0 + a;
  short8 v0 = {0,0,0,0,0,0,0,0}, v1 = {0,0,0,0,0,0,0,0};
  if (s < SA){
    const uint16_t* p = Y + ((size_t)cb*SA + s)*3072 + 2048 + h*64 + g*16;
    v0 = *(const short8*)p;
    v1 = *(const short8*)(p + 8);
  }
  #pragma unroll
  for (int i=0;i<8;i++){ t[a][g*16+i] = (uint16_t)v0[i]; t[a][g*16+8+i] = (uint16_t)v1[i]; }
  __syncthreads();
  short8 w0, w1;
  #pragma unroll
  for (int i=0;i<8;i++){ w0[i] = (short)t[g*16+i][a]; w1[i] = (short)t[g*16+8+i][a]; }
  uint16_t* o = Vt + ((size_t)cbh*64 + a)*SPAD + s0 + g*16;
  *(short8*)o = w0;
  *(short8*)(o + 8) = w1;
}

// ---------------- flash attention, no-max softmax, swapped-QK^T ----------------
// grid 1024 = 128 insts * 8 q-blocks(128 rows); 4 waves, each 2x16 q rows
__global__ __launch_bounds__(256, 4) void attn_k(
    const uint16_t* __restrict__ Y, const uint16_t* __restrict__ Vt,
    uint16_t* __restrict__ att){
  __shared__ __align__(16) uint8_t smK[16384];
  __shared__ __align__(16) uint8_t smV[16384];
  __shared__ __align__(16) uint8_t smP[8192];
  const int tid = threadIdx.x;
  const int lane = tid & 63, wid = tid >> 6;
  const int l15 = lane & 15, l4 = lane >> 4;
  const int i = blockIdx.x;
  // XCD swizzle: all 8 q-blocks of one (cb,h) land on the same XCD
  const int inst = (i & 7) * 16 + (i >> 6);
  const int qb = (i >> 3) & 7;
  const int h = inst & 15, cb = inst >> 4;
  const size_t yrow0 = (size_t)cb * SA;
  const int q0 = qb * 128 + wid * 32;
  const size_t vbase = (size_t)inst * 64 * SPAD;
  const uint16_t* Yk = Y + yrow0 * 3072 + 1024 + h * 64;

  short8 qf[2][2];   // Q pre-scaled by log2(e)/8 at GEMM epilogue
  #pragma unroll
  for (int u = 0; u < 2; ++u){
    const uint16_t* p = Y + (yrow0 + q0 + u*16 + l15) * 3072 + h * 64 + l4 * 8;
    qf[u][0] = *(const short8*)p;
    qf[u][1] = *(const short8*)(p + 32);
  }

  f32x4 o0[4], o1[4];
  float psum0 = 0.f, psum1 = 0.f;
  #pragma unroll
  for (int d = 0; d < 4; ++d){ o0[d] = (f32x4){0,0,0,0}; o1[d] = (f32x4){0,0,0,0}; }

  int koff[2], pwo[4];
  #pragma unroll
  for (int kk = 0; kk < 2; ++kk)
    koff[kk] = (l15*128 + kk*64 + l4*16) ^ ((l15 & 7) << 4);
  #pragma unroll
  for (int nt = 0; nt < 4; ++nt)
    pwo[nt] = (l15*128 + nt*32 + l4*8) ^ ((l15 & 7) << 4);
  uint8_t* const pb = smP + wid * 2048;

  const int srow = lane >> 3, schunk = lane & 7;
  // prologue stage kt=0 into buf0
  #pragma unroll
  for (int j = 0; j < 2; ++j){
    const int cj = wid*2 + j;
    const int row = cj*8 + srow;
    const int gch = schunk ^ (row & 7);
    gload16(Yk + (size_t)row * 3072 + gch*8, smK + cj*1024);
    gload16(Vt + vbase + (size_t)row * SPAD + gch*8, smV + cj*1024);
  }
  __syncthreads();

  int cur = 0;
  for (int kt = 0; kt < 17; ++kt){
    if (kt < 16){
      const int s1n = (kt + 1) * 64;
      const int nb = (cur ^ 1) * 8192;
      #pragma unroll
      for (int j = 0; j < 2; ++j){
        const int cj = wid*2 + j;
        const int row = cj*8 + srow;
        const int gch = schunk ^ (row & 7);
        gload16(Yk + (size_t)(s1n + row) * 3072 + gch*8, smK + nb + cj*1024);
        gload16(Vt + vbase + (size_t)row * SPAD + s1n + gch*8, smV + nb + cj*1024);
      }
    }
    const uint8_t* bK = smK + cur * 8192;
    const uint8_t* bV = smV + cur * 8192;

    // S^T = mfma(K, Q): lane holds P[k = nt*16 + l4*4 + r][q = l15]
    f32x4 sa[4], sb[4];
    #pragma unroll
    for (int nt = 0; nt < 4; ++nt){
      const short8 k0 = *(const short8*)(bK + nt*2048 + koff[0]);
      const short8 k1 = *(const short8*)(bK + nt*2048 + koff[1]);
      sa[nt] = mfma16(k1, qf[0][1], mfma16(k0, qf[0][0], (f32x4){0,0,0,0}));
      sb[nt] = mfma16(k1, qf[1][1], mfma16(k0, qf[1][0], (f32x4){0,0,0,0}));
    }
    if (kt == 16){   // mask keys >= SA (only k_local < 3 valid in tail tile)
      #pragma unroll
      for (int nt = 0; nt < 4; ++nt)
        #pragma unroll
        for (int r = 0; r < 4; ++r){
          if (nt*16 + l4*4 + r >= 3){ sa[nt][r] = -3e38f; sb[nt][r] = -3e38f; }
        }
    }
    // softmax u0: p = exp2(s) (scale pre-folded), pack 4 k-contig vals -> b64
    #pragma unroll
    for (int nt = 0; nt < 4; ++nt){
      const float p0 = __builtin_amdgcn_exp2f(sa[nt][0]);
      const float p1 = __builtin_amdgcn_exp2f(sa[nt][1]);
      const float p2 = __builtin_amdgcn_exp2f(sa[nt][2]);
      const float p3 = __builtin_amdgcn_exp2f(sa[nt][3]);
      psum0 += (p0 + p1) + (p2 + p3);
      uint32_t w0, w1;
      asm("v_cvt_pk_bf16_f32 %0, %1, %2" : "=v"(w0) : "v"(p0), "v"(p1));
      asm("v_cvt_pk_bf16_f32 %0, %1, %2" : "=v"(w1) : "v"(p2), "v"(p3));
      *(u32x2*)(pb + pwo[nt]) = (u32x2){w0, w1};
    }
    short8 vf[4][2];
    #pragma unroll
    for (int dt = 0; dt < 4; ++dt){
      vf[dt][0] = *(const short8*)(bV + dt*2048 + koff[0]);
      vf[dt][1] = *(const short8*)(bV + dt*2048 + koff[1]);
    }
    #pragma unroll
    for (int kk = 0; kk < 2; ++kk){
      const short8 pf = *(const short8*)(pb + koff[kk]);
      #pragma unroll
      for (int dt = 0; dt < 4; ++dt)
        o0[dt] = mfma16(pf, vf[dt][kk], o0[dt]);
    }
    // softmax u1 (after u0's P reads; in-wave LDS ordering)
    #pragma unroll
    for (int nt = 0; nt < 4; ++nt){
      const float p0 = __builtin_amdgcn_exp2f(sb[nt][0]);
      const float p1 = __builtin_amdgcn_exp2f(sb[nt][1]);
      const float p2 = __builtin_amdgcn_exp2f(sb[nt][2]);
      const float p3 = __builtin_amdgcn_exp2f(sb[nt][3]);
      psum1 += (p0 + p1) + (p2 + p3);
      uint32_t w0, w1;
      asm("v_cvt_pk_bf16_f32 %0, %1, %2" : "=v"(w0) : "v"(p0), "v"(p1));
      asm("v_cvt_pk_bf16_f32 %0, %1, %2" : "=v"(w1) : "v"(p2), "v"(p3));
      *(u32x2*)(pb + pwo[nt]) = (u32x2){w0, w1};
    }
    #pragma unroll
    for (int kk = 0; kk < 2; ++kk){
      const short8 pf = *(const short8*)(pb + koff[kk]);
      #pragma unroll
      for (int dt = 0; dt < 4; ++dt)
        o1[dt] = mfma16(pf, vf[dt][kk], o1[dt]);
    }
    __syncthreads();
    cur ^= 1;
  }

  // deferred row-sum: reduce across the 4 k-slice lane groups
  psum0 += __shfl_xor(psum0, 16); psum0 += __shfl_xor(psum0, 32);
  psum1 += __shfl_xor(psum1, 16); psum1 += __shfl_xor(psum1, 32);
  const size_t arow0 = (size_t)cb * 1024 + q0;
  #pragma unroll
  for (int r = 0; r < 4; ++r){
    const float inv0 = 1.f / __shfl(psum0, l4*4 + r);
    const float inv1 = 1.f / __shfl(psum1, l4*4 + r);
    #pragma unroll
    for (int dt = 0; dt < 4; ++dt){
      att[(arow0 + l4*4 + r)*1024 + h*64 + dt*16 + l15] = f2bf(o0[dt][r] * inv0);
      att[(arow0 + 16 + l4*4 + r)*1024 + h*64 + dt*16 + l15] = f2bf(o1[dt][r] * inv1);
    }
  }
}

// ---------------- fused residual + LayerNorm -> f32 out ----------------
__global__ __launch_bounds__(256) void ln_out(
    const uint16_t* __restrict__ Op, const float* __restrict__ cnn,
    const float* __restrict__ llm, const float* __restrict__ g,
    const float* __restrict__ b, float* __restrict__ out){
  const int row = blockIdx.x;
  const int c = row >> 12, bq = row & 4095;
  const int tid = threadIdx.x;
  const ushort4 u = *(const ushort4*)(Op + (size_t)row*1024 + (tid<<2));
  const float4 rv = *(const float4*)((c ? llm : cnn) + (size_t)bq*1024 + (tid<<2));
  const float x0 = bf2f(u.x) + rv.x;
  const float x1 = bf2f(u.y) + rv.y;
  const float x2 = bf2f(u.z) + rv.z;
  const float x3 = bf2f(u.w) + rv.w;
  float s1 = x0+x1+x2+x3;
  float s2 = x0*x0+x1*x1+x2*x2+x3*x3;
  #pragma unroll
  for (int m=1;m<64;m<<=1){ s1 += __shfl_xor(s1,m); s2 += __shfl_xor(s2,m); }
  __shared__ float r1[4], r2[4];
  const int wid = tid >> 6, lane = tid & 63;
  if (lane == 0){ r1[wid] = s1; r2[wid] = s2; }
  __syncthreads();
  s1 = r1[0]+r1[1]+r1[2]+r1[3];
  s2 = r2[0]+r2[1]+r2[2]+r2[3];
  const float mu = s1 * 0.0009765625f;
  const float var = s2 * 0.0009765625f - mu*mu;
  const float rs = rsqrtf(var + 1e-5f);
  const float4 gv = *(const float4*)(g + (tid<<2));
  const float4 bv = *(const float4*)(b + (tid<<2));
  float4 ov;
  ov.x = (x0 - mu)*rs*gv.x + bv.x;
  ov.y = (x1 - mu)*rs*gv.y + bv.y;
  ov.z = (x2 - mu)*rs*gv.z + bv.z;
  ov.w = (x3 - mu)*rs*gv.w + bv.w;
  *(float4*)(out + ((size_t)c << 22) + (size_t)bq*1024 + (tid<<2)) = ov;
}

extern "C" void kernel_launch(void* const* d_in, const int* in_sizes, int n_in,
                              void* d_out, int out_size, void* d_ws, size_t ws_size,
                              hipStream_t stream){
  const float* cnn = (const float*)d_in[0];
  const float* llm = (const float*)d_in[1];
  const float* Wq  = (const float*)d_in[2];
  const float* bq  = (const float*)d_in[3];
  const float* Wk  = (const float*)d_in[4];
  const float* bk  = (const float*)d_in[5];
  const float* Wv  = (const float*)d_in[6];
  const float* bv  = (const float*)d_in[7];
  const float* Wo  = (const float*)d_in[8];
  const float* bo  = (const float*)d_in[9];
  const float* lng = (const float*)d_in[10];
  const float* lnb = (const float*)d_in[11];
  const float* ee  = (const float*)d_in[12];
  const float* em  = (const float*)d_in[13];
  const float* ep  = (const float*)d_in[14];

  uint8_t* ws = (uint8_t*)d_ws;
  uint16_t* X    = (uint16_t*)(ws + 0);           // 17,039,360 B
  uint16_t* W    = (uint16_t*)(ws + 17039360);    //  8,388,608 B
  float*    bias = (float*)   (ws + 25427968);    //     16,384 B
  uint16_t* Y    = (uint16_t*)(ws + 25444352);    // 51,118,080 B
  uint16_t* Vt   = (uint16_t*)(ws + 76562432);    // 17,825,792 B
  uint16_t* att  = (uint16_t*)(ws + 94388224);    // 16,777,216 B
  uint16_t* Op   = X;                              // reuse X region
  float* out = (float*)d_out;

  prep_wb<<<4100, 256, 0, stream>>>(Wq, Wk, Wv, Wo, bq, bk, bv, bo, W, bias);
  prep_X<<<MPAD, 256, 0, stream>>>(cnn, llm, ee, em, ep, X);
  gemm_bt<<<dim3(24, 65), 256, 0, stream>>>(X, W, bias, Y, 1024, 1024, 1024, 3072, QSCALE, 1024);
  vtrans<<<128*17, 256, 0, stream>>>(Y, Vt);
  attn_k<<<1024, 256, 0, stream>>>(Y, Vt, att);
  gemm_bt<<<dim3(8, 64), 256, 0, stream>>>(att, W + 3145728, bias + 3072, Op, 1024, 1024, 1024, 1024, 1.0f, 0);
  ln_out<<<ATTM, 256, 0, stream>>>(Op, cnn, llm, lng, lnb, out);
}

// Round 3
// 184.075 us; speedup vs baseline: 1.4552x; 1.0385x over previous
//
#include <hip/hip_runtime.h>
#include <stdint.h>

#define SA 1027
#define MROWS 8216
#define MPAD 8448
#define SPAD 1088
#define ATTM 8192

typedef __attribute__((ext_vector_type(8))) short short8;
typedef __attribute__((ext_vector_type(4))) float f32x4;
typedef __attribute__((ext_vector_type(2))) unsigned int u32x2;

typedef const __attribute__((address_space(1))) uint8_t* gas1;
typedef __attribute__((address_space(3))) uint8_t* las3;

__device__ __forceinline__ void gload16(const void* g, void* l){
  __builtin_amdgcn_global_load_lds((gas1)g, (las3)l, 16, 0, 0);
}

__device__ __forceinline__ uint16_t f2bf(float f){
  uint32_t x = __builtin_bit_cast(uint32_t, f);
  x = (x + 0x7fffu + ((x >> 16) & 1u)) >> 16;
  return (uint16_t)x;
}
__device__ __forceinline__ float bf2f(uint16_t u){
  uint32_t x = ((uint32_t)u) << 16;
  return __builtin_bit_cast(float, x);
}

__device__ __forceinline__ f32x4 mfma16(short8 a, short8 b, f32x4 c){
  return __builtin_amdgcn_mfma_f32_16x16x32_bf16(a, b, c, 0, 0, 0);
}

// log2(e)/8 — folded into Q at the QKV GEMM epilogue
#define QSCALE 0.18033688011112042f

// ---------------- prep: weights/biases -> bf16 ws ----------------
__global__ __launch_bounds__(256) void prep_wb(
    const float* __restrict__ Wq, const float* __restrict__ Wk,
    const float* __restrict__ Wv, const float* __restrict__ Wo,
    const float* __restrict__ bq, const float* __restrict__ bk,
    const float* __restrict__ bv, const float* __restrict__ bo,
    uint16_t* __restrict__ W, float* __restrict__ bias){
  const int gid = blockIdx.x*256 + threadIdx.x;
  if (gid < 1048576){
    const int w = gid >> 18;
    const int off = (gid & 262143) << 2;
    const float* src = (w==0) ? Wq : (w==1) ? Wk : (w==2) ? Wv : Wo;
    const float4 v = *(const float4*)(src + off);
    ushort4 u;
    u.x = f2bf(v.x); u.y = f2bf(v.y); u.z = f2bf(v.z); u.w = f2bf(v.w);
    *(ushort4*)(W + ((size_t)w << 20) + off) = u;
  } else if (gid < 1048576 + 1024){
    const int i = (gid - 1048576) << 2;
    const int w = i >> 10;
    const int off = i & 1023;
    const float* src = (w==0) ? bq : (w==1) ? bk : (w==2) ? bv : bo;
    *(float4*)(bias + i) = *(const float4*)(src + off);
  }
}

// ---------------- prep: X = [aug_cnn; aug_llm] bf16, padded to MPAD rows ----
__global__ __launch_bounds__(256) void prep_X(
    const float* __restrict__ cnn, const float* __restrict__ llm,
    const float* __restrict__ ee, const float* __restrict__ em,
    const float* __restrict__ ep, uint16_t* __restrict__ X){
  const int row = blockIdx.x;
  const int c4 = threadIdx.x << 2;
  float4 v = {0.f,0.f,0.f,0.f};
  if (row < MROWS){
    const int cb = row / SA;
    const int s = row - cb*SA;
    const int c = cb >> 2, b = cb & 3;
    const float* src;
    if (s < 1024) src = (c ? llm : cnn) + ((size_t)(b*1024 + s))*1024 + c4;
    else src = ((s == 1024) ? ee : (s == 1025) ? em : ep) + c4;
    v = *(const float4*)src;
  }
  ushort4 u;
  u.x = f2bf(v.x); u.y = f2bf(v.y); u.z = f2bf(v.z); u.w = f2bf(v.w);
  *(ushort4*)(X + (size_t)row*1024 + c4) = u;
}

// ---------------- 256x256 8-phase GEMM (T2+T3+T4+T5) ----------------
// C[m][n] = (sum_k A[m][k]*B[n][k] + bias[n]) * (n<qcols ? qscale : 1)
// 512 threads = 8 waves (2M x 4N). BK=64. LDS 128KB dynamic, dbuf.
// Per K-tile: 4 phases, each {ds_read subtile | stage 1 half-tile -> bar ->
// lgkmcnt(0) -> setprio(1) 16 MFMA setprio(0) -> bar}; vmcnt(4) once/tile.
__global__ __launch_bounds__(512) void gemm256k(
    const uint16_t* __restrict__ A, const uint16_t* __restrict__ B,
    const float* __restrict__ bias, uint16_t* __restrict__ C,
    int K, int lda, int ldb, int ldc, int nbn, float qscale, int qcols){
  extern __shared__ uint8_t lds[];   // buf b: A at b*65536, B at +32768
  const int tid = threadIdx.x;
  const int lane = tid & 63, wid = tid >> 6;
  const int l15 = lane & 15, l4 = lane >> 4;
  const int wm = wid >> 2, wn = wid & 3;
  // bijective XCD swizzle (m204)
  const int nwg = gridDim.x;
  const int q8 = nwg >> 3, r8 = nwg & 7;
  const int xcd = blockIdx.x & 7, loc = blockIdx.x >> 3;
  const int wg = (xcd < r8 ? xcd*(q8+1) : r8*(q8+1) + (xcd-r8)*q8) + loc;
  const int bm = wg / nbn, bn = wg % nbn;

  const uint16_t* Ag = A + (size_t)bm*256*lda;
  const uint16_t* Bg = B + (size_t)bn*256*ldb;

  // staging: per half-tile (128 rows x 64 cols bf16 = 16KB) each wave fills
  // 2 contiguous 1KB chunks; pre-swizzled global source (rule 21)
  const int srow8 = lane >> 3;
  const int gch = (lane & 7) ^ srow8;
  const int c0 = wid*2, c1 = c0 + 1;
  const size_t ga0 = (size_t)(c0*8 + srow8)*lda + gch*8;
  const size_t ga1 = (size_t)(c1*8 + srow8)*lda + gch*8;
  const size_t gb0 = (size_t)(c0*8 + srow8)*ldb + gch*8;
  const size_t gb1 = (size_t)(c1*8 + srow8)*ldb + gch*8;

#define STG_A(buf, H, kt) do { \
    gload16(Ag + (size_t)(H)*128*lda + (size_t)(kt)*64 + ga0, lds + (buf)*65536 + (H)*16384 + c0*1024); \
    gload16(Ag + (size_t)(H)*128*lda + (size_t)(kt)*64 + ga1, lds + (buf)*65536 + (H)*16384 + c1*1024); \
  } while(0)
#define STG_B(buf, H, kt) do { \
    gload16(Bg + (size_t)(H)*128*ldb + (size_t)(kt)*64 + gb0, lds + (buf)*65536 + 32768 + (H)*16384 + c0*1024); \
    gload16(Bg + (size_t)(H)*128*ldb + (size_t)(kt)*64 + gb1, lds + (buf)*65536 + 32768 + (H)*16384 + c1*1024); \
  } while(0)

  int koff[2];
  koff[0] = (l4*16) ^ ((l15 & 7) << 4);
  koff[1] = (64 + l4*16) ^ ((l15 & 7) << 4);
  const int arow = (wm*128 + l15) * 128;
  const int brow = (wn*64 + l15) * 128;

  f32x4 acc[8][4];
  #pragma unroll
  for (int i = 0; i < 8; ++i)
    #pragma unroll
    for (int j = 0; j < 4; ++j) acc[i][j] = (f32x4){0.f,0.f,0.f,0.f};

  const int NT = K >> 6;
  // prologue: tile0 full + B halves of tile1 (12 loads); allow 4 outstanding
  STG_A(0,0,0); STG_A(0,1,0); STG_B(0,0,0); STG_B(0,1,0);
  STG_B(1,0,1); STG_B(1,1,1);
  asm volatile("s_waitcnt vmcnt(4)" ::: "memory");
  __builtin_amdgcn_s_barrier();

  for (int s = 0; s < NT; ++s){
    const int b = s & 1;
    const uint8_t* La = lds + b*65536;
    const uint8_t* Lb = La + 32768;
    const int sn1 = (s+1 < NT) ? s+1 : s;   // clamped (keeps vmcnt exact)
    const int sn2 = (s+2 < NT) ? s+2 : s;
    const int nb = b ^ 1;
    short8 af[4][2], bf0[2][2], bf1[2][2];

    // ---- phase 0: quad (mh=0, nh=0)
    #pragma unroll
    for (int i = 0; i < 4; ++i){
      af[i][0] = *(const short8*)(La + arow + i*2048 + koff[0]);
      af[i][1] = *(const short8*)(La + arow + i*2048 + koff[1]);
    }
    #pragma unroll
    for (int j = 0; j < 2; ++j){
      bf0[j][0] = *(const short8*)(Lb + brow + j*2048 + koff[0]);
      bf0[j][1] = *(const short8*)(Lb + brow + j*2048 + koff[1]);
    }
    STG_A(nb, 0, sn1);
    __builtin_amdgcn_s_barrier();
    asm volatile("s_waitcnt lgkmcnt(0)" ::: "memory");
    __builtin_amdgcn_sched_barrier(0);
    __builtin_amdgcn_s_setprio(1);
    #pragma unroll
    for (int i = 0; i < 4; ++i)
      #pragma unroll
      for (int j = 0; j < 2; ++j)
        acc[i][j] = mfma16(af[i][1], bf0[j][1], mfma16(af[i][0], bf0[j][0], acc[i][j]));
    __builtin_amdgcn_s_setprio(0);
    __builtin_amdgcn_s_barrier();

    // ---- phase 1: quad (mh=0, nh=1)
    #pragma unroll
    for (int j = 0; j < 2; ++j){
      bf1[j][0] = *(const short8*)(Lb + brow + (j+2)*2048 + koff[0]);
      bf1[j][1] = *(const short8*)(Lb + brow + (j+2)*2048 + koff[1]);
    }
    STG_A(nb, 1, sn1);
    __builtin_amdgcn_s_barrier();
    asm volatile("s_waitcnt lgkmcnt(0)" ::: "memory");
    __builtin_amdgcn_sched_barrier(0);
    __builtin_amdgcn_s_setprio(1);
    #pragma unroll
    for (int i = 0; i < 4; ++i)
      #pragma unroll
      for (int j = 0; j < 2; ++j)
        acc[i][j+2] = mfma16(af[i][1], bf1[j][1], mfma16(af[i][0], bf1[j][0], acc[i][j+2]));
    __builtin_amdgcn_s_setprio(0);
    __builtin_amdgcn_s_barrier();

    // ---- phase 2: quad (mh=1, nh=1) — af overwritten with rows +64
    #pragma unroll
    for (int i = 0; i < 4; ++i){
      af[i][0] = *(const short8*)(La + 8192 + arow + i*2048 + koff[0]);
      af[i][1] = *(const short8*)(La + 8192 + arow + i*2048 + koff[1]);
    }
    STG_B(b, 0, sn2);   // tile s+2 shares buffer b; B-region dead after ph1 bar
    __builtin_amdgcn_s_barrier();
    asm volatile("s_waitcnt lgkmcnt(0)" ::: "memory");
    __builtin_amdgcn_sched_barrier(0);
    __builtin_amdgcn_s_setprio(1);
    #pragma unroll
    for (int i = 0; i < 4; ++i)
      #pragma unroll
      for (int j = 0; j < 2; ++j)
        acc[i+4][j+2] = mfma16(af[i][1], bf1[j][1], mfma16(af[i][0], bf1[j][0], acc[i+4][j+2]));
    __builtin_amdgcn_s_setprio(0);
    __builtin_amdgcn_s_barrier();

    // ---- phase 3: quad (mh=1, nh=0) — regs only
    STG_B(b, 1, sn2);
    __builtin_amdgcn_s_barrier();
    __builtin_amdgcn_s_setprio(1);
    #pragma unroll
    for (int i = 0; i < 4; ++i)
      #pragma unroll
      for (int j = 0; j < 2; ++j)
        acc[i+4][j] = mfma16(af[i][1], bf0[j][1], mfma16(af[i][0], bf0[j][0], acc[i+4][j]));
    __builtin_amdgcn_s_setprio(0);
    asm volatile("s_waitcnt vmcnt(4)" ::: "memory");  // tile s+1 landed; B(s+2) in flight
    __builtin_amdgcn_s_barrier();
  }

  #pragma unroll
  for (int j = 0; j < 4; ++j){
    const int n = bn*256 + wn*64 + j*16 + l15;
    const float bb = bias[n];
    const float sc = (n < qcols) ? qscale : 1.0f;
    #pragma unroll
    for (int i = 0; i < 8; ++i){
      const size_t m0 = (size_t)bm*256 + wm*128 + i*16 + l4*4;
      #pragma unroll
      for (int r = 0; r < 4; ++r)
        C[(m0 + r)*ldc + n] = f2bf((acc[i][j][r] + bb) * sc);
    }
  }
#undef STG_A
#undef STG_B
}

// ---------------- V transpose: Vt[(cb*16+h)*64 + d][s], zero-padded to SPAD --
__global__ __launch_bounds__(256) void vtrans(
    const uint16_t* __restrict__ Y, uint16_t* __restrict__ Vt){
  __shared__ uint16_t t[64][65];
  const int bid = blockIdx.x;
  const int st = bid % 17, cbh = bid / 17;
  const int s0 = st*64;
  const int tid = threadIdx.x;
  const int a = tid >> 2, g = tid & 3;
  const int cb = cbh >> 4, h = cbh & 15;
  const int s = s0 + a;
  short8 v0 = {0,0,0,0,0,0,0,0}, v1 = {0,0,0,0,0,0,0,0};
  if (s < SA){
    const uint16_t* p = Y + ((size_t)cb*SA + s)*3072 + 2048 + h*64 + g*16;
    v0 = *(const short8*)p;
    v1 = *(const short8*)(p + 8);
  }
  #pragma unroll
  for (int i=0;i<8;i++){ t[a][g*16+i] = (uint16_t)v0[i]; t[a][g*16+8+i] = (uint16_t)v1[i]; }
  __syncthreads();
  short8 w0, w1;
  #pragma unroll
  for (int i=0;i<8;i++){ w0[i] = (short)t[g*16+i][a]; w1[i] = (short)t[g*16+8+i][a]; }
  uint16_t* o = Vt + ((size_t)cbh*64 + a)*SPAD + s0 + g*16;
  *(short8*)o = w0;
  *(short8*)(o + 8) = w1;
}

// ---------------- flash attention, no-max softmax, swapped-QK^T ----------------
__global__ __launch_bounds__(256, 4) void attn_k(
    const uint16_t* __restrict__ Y, const uint16_t* __restrict__ Vt,
    uint16_t* __restrict__ att){
  __shared__ __align__(16) uint8_t smK[16384];
  __shared__ __align__(16) uint8_t smV[16384];
  __shared__ __align__(16) uint8_t smP[8192];
  const int tid = threadIdx.x;
  const int lane = tid & 63, wid = tid >> 6;
  const int l15 = lane & 15, l4 = lane >> 4;
  const int i = blockIdx.x;
  const int inst = (i & 7) * 16 + (i >> 6);
  const int qb = (i >> 3) & 7;
  const int h = inst & 15, cb = inst >> 4;
  const size_t yrow0 = (size_t)cb * SA;
  const int q0 = qb * 128 + wid * 32;
  const size_t vbase = (size_t)inst * 64 * SPAD;
  const uint16_t* Yk = Y + yrow0 * 3072 + 1024 + h * 64;

  short8 qf[2][2];
  #pragma unroll
  for (int u = 0; u < 2; ++u){
    const uint16_t* p = Y + (yrow0 + q0 + u*16 + l15) * 3072 + h * 64 + l4 * 8;
    qf[u][0] = *(const short8*)p;
    qf[u][1] = *(const short8*)(p + 32);
  }

  f32x4 o0[4], o1[4];
  float psum0 = 0.f, psum1 = 0.f;
  #pragma unroll
  for (int d = 0; d < 4; ++d){ o0[d] = (f32x4){0,0,0,0}; o1[d] = (f32x4){0,0,0,0}; }

  int koff[2], pwo[4];
  #pragma unroll
  for (int kk = 0; kk < 2; ++kk)
    koff[kk] = (l15*128 + kk*64 + l4*16) ^ ((l15 & 7) << 4);
  #pragma unroll
  for (int nt = 0; nt < 4; ++nt)
    pwo[nt] = (l15*128 + nt*32 + l4*8) ^ ((l15 & 7) << 4);
  uint8_t* const pb = smP + wid * 2048;

  const int srow = lane >> 3, schunk = lane & 7;
  #pragma unroll
  for (int j = 0; j < 2; ++j){
    const int cj = wid*2 + j;
    const int row = cj*8 + srow;
    const int gch = schunk ^ (row & 7);
    gload16(Yk + (size_t)row * 3072 + gch*8, smK + cj*1024);
    gload16(Vt + vbase + (size_t)row * SPAD + gch*8, smV + cj*1024);
  }
  __syncthreads();

  int cur = 0;
  for (int kt = 0; kt < 17; ++kt){
    if (kt < 16){
      const int s1n = (kt + 1) * 64;
      const int nb = (cur ^ 1) * 8192;
      #pragma unroll
      for (int j = 0; j < 2; ++j){
        const int cj = wid*2 + j;
        const int row = cj*8 + srow;
        const int gch = schunk ^ (row & 7);
        gload16(Yk + (size_t)(s1n + row) * 3072 + gch*8, smK + nb + cj*1024);
        gload16(Vt + vbase + (size_t)row * SPAD + s1n + gch*8, smV + nb + cj*1024);
      }
    }
    const uint8_t* bK = smK + cur * 8192;
    const uint8_t* bV = smV + cur * 8192;

    f32x4 sa[4], sb[4];
    #pragma unroll
    for (int nt = 0; nt < 4; ++nt){
      const short8 k0 = *(const short8*)(bK + nt*2048 + koff[0]);
      const short8 k1 = *(const short8*)(bK + nt*2048 + koff[1]);
      sa[nt] = mfma16(k1, qf[0][1], mfma16(k0, qf[0][0], (f32x4){0,0,0,0}));
      sb[nt] = mfma16(k1, qf[1][1], mfma16(k0, qf[1][0], (f32x4){0,0,0,0}));
    }
    if (kt == 16){
      #pragma unroll
      for (int nt = 0; nt < 4; ++nt)
        #pragma unroll
        for (int r = 0; r < 4; ++r){
          if (nt*16 + l4*4 + r >= 3){ sa[nt][r] = -3e38f; sb[nt][r] = -3e38f; }
        }
    }
    #pragma unroll
    for (int nt = 0; nt < 4; ++nt){
      const float p0 = __builtin_amdgcn_exp2f(sa[nt][0]);
      const float p1 = __builtin_amdgcn_exp2f(sa[nt][1]);
      const float p2 = __builtin_amdgcn_exp2f(sa[nt][2]);
      const float p3 = __builtin_amdgcn_exp2f(sa[nt][3]);
      psum0 += (p0 + p1) + (p2 + p3);
      uint32_t w0, w1;
      asm("v_cvt_pk_bf16_f32 %0, %1, %2" : "=v"(w0) : "v"(p0), "v"(p1));
      asm("v_cvt_pk_bf16_f32 %0, %1, %2" : "=v"(w1) : "v"(p2), "v"(p3));
      *(u32x2*)(pb + pwo[nt]) = (u32x2){w0, w1};
    }
    short8 vf[4][2];
    #pragma unroll
    for (int dt = 0; dt < 4; ++dt){
      vf[dt][0] = *(const short8*)(bV + dt*2048 + koff[0]);
      vf[dt][1] = *(const short8*)(bV + dt*2048 + koff[1]);
    }
    #pragma unroll
    for (int kk = 0; kk < 2; ++kk){
      const short8 pf = *(const short8*)(pb + koff[kk]);
      #pragma unroll
      for (int dt = 0; dt < 4; ++dt)
        o0[dt] = mfma16(pf, vf[dt][kk], o0[dt]);
    }
    #pragma unroll
    for (int nt = 0; nt < 4; ++nt){
      const float p0 = __builtin_amdgcn_exp2f(sb[nt][0]);
      const float p1 = __builtin_amdgcn_exp2f(sb[nt][1]);
      const float p2 = __builtin_amdgcn_exp2f(sb[nt][2]);
      const float p3 = __builtin_amdgcn_exp2f(sb[nt][3]);
      psum1 += (p0 + p1) + (p2 + p3);
      uint32_t w0, w1;
      asm("v_cvt_pk_bf16_f32 %0, %1, %2" : "=v"(w0) : "v"(p0), "v"(p1));
      asm("v_cvt_pk_bf16_f32 %0, %1, %2" : "=v"(w1) : "v"(p2), "v"(p3));
      *(u32x2*)(pb + pwo[nt]) = (u32x2){w0, w1};
    }
    #pragma unroll
    for (int kk = 0; kk < 2; ++kk){
      const short8 pf = *(const short8*)(pb + koff[kk]);
      #pragma unroll
      for (int dt = 0; dt < 4; ++dt)
        o1[dt] = mfma16(pf, vf[dt][kk], o1[dt]);
    }
    __syncthreads();
    cur ^= 1;
  }

  psum0 += __shfl_xor(psum0, 16); psum0 += __shfl_xor(psum0, 32);
  psum1 += __shfl_xor(psum1, 16); psum1 += __shfl_xor(psum1, 32);
  const size_t arow0 = (size_t)cb * 1024 + q0;
  #pragma unroll
  for (int r = 0; r < 4; ++r){
    const float inv0 = 1.f / __shfl(psum0, l4*4 + r);
    const float inv1 = 1.f / __shfl(psum1, l4*4 + r);
    #pragma unroll
    for (int dt = 0; dt < 4; ++dt){
      att[(arow0 + l4*4 + r)*1024 + h*64 + dt*16 + l15] = f2bf(o0[dt][r] * inv0);
      att[(arow0 + 16 + l4*4 + r)*1024 + h*64 + dt*16 + l15] = f2bf(o1[dt][r] * inv1);
    }
  }
}

// ---------------- fused residual + LayerNorm -> f32 out ----------------
__global__ __launch_bounds__(256) void ln_out(
    const uint16_t* __restrict__ Op, const float* __restrict__ cnn,
    const float* __restrict__ llm, const float* __restrict__ g,
    const float* __restrict__ b, float* __restrict__ out){
  const int row = blockIdx.x;
  const int c = row >> 12, bq = row & 4095;
  const int tid = threadIdx.x;
  const ushort4 u = *(const ushort4*)(Op + (size_t)row*1024 + (tid<<2));
  const float4 rv = *(const float4*)((c ? llm : cnn) + (size_t)bq*1024 + (tid<<2));
  const float x0 = bf2f(u.x) + rv.x;
  const float x1 = bf2f(u.y) + rv.y;
  const float x2 = bf2f(u.z) + rv.z;
  const float x3 = bf2f(u.w) + rv.w;
  float s1 = x0+x1+x2+x3;
  float s2 = x0*x0+x1*x1+x2*x2+x3*x3;
  #pragma unroll
  for (int m=1;m<64;m<<=1){ s1 += __shfl_xor(s1,m); s2 += __shfl_xor(s2,m); }
  __shared__ float r1[4], r2[4];
  const int wid = tid >> 6, lane = tid & 63;
  if (lane == 0){ r1[wid] = s1; r2[wid] = s2; }
  __syncthreads();
  s1 = r1[0]+r1[1]+r1[2]+r1[3];
  s2 = r2[0]+r2[1]+r2[2]+r2[3];
  const float mu = s1 * 0.0009765625f;
  const float var = s2 * 0.0009765625f - mu*mu;
  const float rs = rsqrtf(var + 1e-5f);
  const float4 gv = *(const float4*)(g + (tid<<2));
  const float4 bv = *(const float4*)(b + (tid<<2));
  float4 ov;
  ov.x = (x0 - mu)*rs*gv.x + bv.x;
  ov.y = (x1 - mu)*rs*gv.y + bv.y;
  ov.z = (x2 - mu)*rs*gv.z + bv.z;
  ov.w = (x3 - mu)*rs*gv.w + bv.w;
  *(float4*)(out + ((size_t)c << 22) + (size_t)bq*1024 + (tid<<2)) = ov;
}

extern "C" void kernel_launch(void* const* d_in, const int* in_sizes, int n_in,
                              void* d_out, int out_size, void* d_ws, size_t ws_size,
                              hipStream_t stream){
  const float* cnn = (const float*)d_in[0];
  const float* llm = (const float*)d_in[1];
  const float* Wq  = (const float*)d_in[2];
  const float* bq  = (const float*)d_in[3];
  const float* Wk  = (const float*)d_in[4];
  const float* bk  = (const float*)d_in[5];
  const float* Wv  = (const float*)d_in[6];
  const float* bv  = (const float*)d_in[7];
  const float* Wo  = (const float*)d_in[8];
  const float* bo  = (const float*)d_in[9];
  const float* lng = (const float*)d_in[10];
  const float* lnb = (const float*)d_in[11];
  const float* ee  = (const float*)d_in[12];
  const float* em  = (const float*)d_in[13];
  const float* ep  = (const float*)d_in[14];

  uint8_t* ws = (uint8_t*)d_ws;
  uint16_t* X    = (uint16_t*)(ws + 0);           // 8448*1024*2 = 17,301,504
  uint16_t* W    = (uint16_t*)(ws + 17301504);    //  8,388,608
  float*    bias = (float*)   (ws + 25690112);    //     16,384
  uint16_t* Y    = (uint16_t*)(ws + 25706496);    // 8448*3072*2 = 51,904,512
  uint16_t* Vt   = (uint16_t*)(ws + 77611008);    // 17,825,792 (ends 95,436,800)
  uint16_t* att  = X;                              // X dead after QKV GEMM
  uint16_t* Op   = Y;                              // Y dead after attn
  float* out = (float*)d_out;

  hipFuncSetAttribute((const void*)gemm256k,
                      hipFuncAttributeMaxDynamicSharedMemorySize, 131072);

  prep_wb<<<4100, 256, 0, stream>>>(Wq, Wk, Wv, Wo, bq, bk, bv, bo, W, bias);
  prep_X<<<MPAD, 256, 0, stream>>>(cnn, llm, ee, em, ep, X);
  gemm256k<<<396, 512, 131072, stream>>>(X, W, bias, Y, 1024, 1024, 1024, 3072, 12, QSCALE, 1024);
  vtrans<<<128*17, 256, 0, stream>>>(Y, Vt);
  attn_k<<<1024, 256, 0, stream>>>(Y, Vt, att);
  gemm256k<<<128, 512, 131072, stream>>>(att, W + 3145728, bias + 3072, Op, 1024, 1024, 1024, 1024, 4, 1.0f, 0);
  ln_out<<<ATTM, 256, 0, stream>>>(Op, cnn, llm, lng, lnb, out);
}